// Round 5
// baseline (101.071 us; speedup 1.0000x reference)
//
#include <hip/hip_runtime.h>

typedef __attribute__((ext_vector_type(8))) short bf16x8;
typedef __attribute__((ext_vector_type(16))) float f32x16;
typedef unsigned int u32;

#define LOG2E 1.44269504088896f

__device__ __forceinline__ short f2bf(float f) {
    union { float f; unsigned u; } v; v.f = f;
    unsigned r = v.u + 0x7fffu + ((v.u >> 16) & 1u);
    return (short)(r >> 16);
}

#if __has_builtin(__builtin_amdgcn_exp2f)
#define EXP2(x) __builtin_amdgcn_exp2f(x)
#else
#define EXP2(x) __builtin_exp2f(x)
#endif

__device__ __forceinline__ u32 pack_bf16_trunc(float lo, float hi) {
#if __has_builtin(__builtin_amdgcn_perm)
    return __builtin_amdgcn_perm(__float_as_uint(hi), __float_as_uint(lo), 0x07060302u);
#else
    return (__float_as_uint(hi) & 0xFFFF0000u) | (__float_as_uint(lo) >> 16);
#endif
}

__device__ __forceinline__ f32x16 zero16() {
    f32x16 v;
    #pragma unroll
    for (int i = 0; i < 16; ++i) v[i] = 0.f;
    return v;
}

// async global->LDS DMA, 16B per lane, wave-uniform LDS base + lane*16
__device__ __forceinline__ void gload_lds16(const short* g, short* l) {
    __builtin_amdgcn_global_load_lds(
        (const __attribute__((address_space(1))) void*)g,
        (__attribute__((address_space(3))) void*)l, 16, 0, 0);
}

// ---------------- prep (unchanged; layouts verified absmax=0) ----------------
// blocks 0..255  : per-center scalars (log2e-scaled): ns=-s*L, nscs=-s*||c||^2*L, ts=2s*L
// blocks 256..383: centers -> cfrag, 32x32x16 A-frag order: slot s=[c][ks][lane]
// blocks 384..447: W -> wfrag, 32x32x16 B-frag order: slot s=[c][ct][k2][lane]
__global__ __launch_bounds__(256) void rbf_prep(
    const float* __restrict__ centers, const float* __restrict__ sigmas,
    const float* __restrict__ W,
    short* __restrict__ cfrag, short* __restrict__ wfrag,
    float* __restrict__ ns, float* __restrict__ nscs, float* __restrict__ ts)
{
    const int tid = threadIdx.x;
    const int bid = blockIdx.x;
    if (bid < 256) {
        const int lane = tid & 63, w = tid >> 6;
        const int row = bid * 4 + w;
        const float4 v = ((const float4*)(centers + (size_t)row * 256))[lane];
        float s = v.x*v.x + v.y*v.y + v.z*v.z + v.w*v.w;
        #pragma unroll
        for (int off = 32; off >= 1; off >>= 1) s += __shfl_xor(s, off, 64);
        if (lane == 0) {
            const float sg = sigmas[row];
            ns[row]   = -sg * LOG2E;
            nscs[row] = -sg * s * LOG2E;
            ts[row]   = 2.0f * sg * LOG2E;
        }
    } else if (bid < 384) {
        const int s = (bid - 256) * 256 + tid;               // 0..32767
        const int c = s >> 10, ks = (s >> 6) & 15, lane = s & 63;
        const int m = c * 32 + (lane & 31);
        const int k = ks * 16 + (lane >> 5) * 8;
        const float4 a = *(const float4*)(centers + (size_t)m * 256 + k);
        const float4 b = *(const float4*)(centers + (size_t)m * 256 + k + 4);
        bf16x8 t;
        t[0]=f2bf(a.x); t[1]=f2bf(a.y); t[2]=f2bf(a.z); t[3]=f2bf(a.w);
        t[4]=f2bf(b.x); t[5]=f2bf(b.y); t[6]=f2bf(b.z); t[7]=f2bf(b.w);
        ((bf16x8*)cfrag)[s] = t;
    } else {
        const int s = (bid - 384) * 256 + tid;               // 0..16383
        const int c = s >> 9, ct = (s >> 7) & 3, k2 = (s >> 6) & 1, lane = s & 63;
        const int o = ct * 32 + (lane & 31);
        const int m = c * 32 + k2 * 16 + (lane >> 5) * 8;
        const float4 a = *(const float4*)(W + (size_t)o * 1024 + m);
        const float4 b = *(const float4*)(W + (size_t)o * 1024 + m + 4);
        bf16x8 t;
        t[0]=f2bf(a.x); t[1]=f2bf(a.y); t[2]=f2bf(a.z); t[3]=f2bf(a.w);
        t[4]=f2bf(b.x); t[5]=f2bf(b.y); t[6]=f2bf(b.z); t[7]=f2bf(b.w);
        ((bf16x8*)wfrag)[s] = t;
    }
}

// ---------------- main: FAT waves (64 q-rows/wave) + global_load_lds staging ----------------
// 256 blocks x 4 waves = 1 block/CU, 1 wave/SIMD. Each A-frag LDS read feeds
// TWO MFMAs (tiles t=0,1) -> LDS traffic halved vs round 4. Staging is pure
// DMA (no VGPR round-trip, no ds_write). One barrier per chunk.
__global__ __launch_bounds__(256, 1) void rbf_main(
    const float* __restrict__ x, const float* __restrict__ bvec,
    const short* __restrict__ cfrag, const short* __restrict__ wfrag,
    const float* __restrict__ ns, const float* __restrict__ nscs,
    const float* __restrict__ ts, float* __restrict__ out)
{
    __shared__ short Cb[2][8192];   // 16 KB/buf: 16 frags x 1 KB, [frag][lane] linear
    __shared__ short Wb[2][4096];   //  8 KB/buf: 8 frags x 1 KB

    const int tid = threadIdx.x;
    const int lane = tid & 63;
    const int l31 = lane & 31;
    const int hi = lane >> 5;
    const int w = tid >> 6;
    const int qb = blockIdx.x * 256 + w * 64;

    // ---- stage chunk 0 into buf 0 (DMA proceeds under the X prologue) ----
    #pragma unroll
    for (int i = 0; i < 4; ++i) {
        const int f = w * 4 + i;
        gload_lds16(cfrag + (size_t)(f * 64 + lane) * 8, &Cb[0][f * 512]);
    }
    #pragma unroll
    for (int i = 0; i < 2; ++i) {
        const int f = w * 2 + i;
        gload_lds16(wfrag + (size_t)(f * 64 + lane) * 8, &Wb[0][f * 512]);
    }

    // ---- X: two 32-row tiles in registers (reused all 32 chunks) + xs ----
    bf16x8 xb[2][16];
    float xs[2];
    #pragma unroll
    for (int t = 0; t < 2; ++t) {
        const float* xr = x + (size_t)(qb + t * 32 + l31) * 256 + hi * 8;
        float ss = 0.f;
        #pragma unroll
        for (int ks = 0; ks < 16; ++ks) {
            const float4 a = *(const float4*)(xr + ks * 16);
            const float4 b = *(const float4*)(xr + ks * 16 + 4);
            ss += a.x*a.x + a.y*a.y + a.z*a.z + a.w*a.w
                + b.x*b.x + b.y*b.y + b.z*b.z + b.w*b.w;
            bf16x8 tv;
            tv[0]=f2bf(a.x); tv[1]=f2bf(a.y); tv[2]=f2bf(a.z); tv[3]=f2bf(a.w);
            tv[4]=f2bf(b.x); tv[5]=f2bf(b.y); tv[6]=f2bf(b.z); tv[7]=f2bf(b.w);
            xb[t][ks] = tv;
        }
        ss += __shfl_xor(ss, 32, 64);
        xs[t] = ss;
    }

    f32x16 acc[2][4];
    #pragma unroll
    for (int t = 0; t < 2; ++t)
        #pragma unroll
        for (int ct = 0; ct < 4; ++ct) acc[t][ct] = zero16();

    __syncthreads();   // own vmcnt(0) drains chunk-0 DMA; barrier collects all waves

    int buf = 0;
    for (int c = 0; c < 32; ++c) {
        // ---- issue next chunk's DMA into buf^1 (safe: barrier at end of c-1
        //      guaranteed everyone finished reading buf^1) ----
        if (c < 31) {
            const short* cs = cfrag + (size_t)(c + 1) * 8192;
            const short* wsrc = wfrag + (size_t)(c + 1) * 4096;
            #pragma unroll
            for (int i = 0; i < 4; ++i) {
                const int f = w * 4 + i;
                gload_lds16(cs + (size_t)(f * 64 + lane) * 8, &Cb[buf ^ 1][f * 512]);
            }
            #pragma unroll
            for (int i = 0; i < 2; ++i) {
                const int f = w * 2 + i;
                gload_lds16(wsrc + (size_t)(f * 64 + lane) * 8, &Wb[buf ^ 1][f * 512]);
            }
        }

        // ---- W-frags to regs (latency hides under S-phase) ----
        bf16x8 wf[8];
        const bf16x8* wbl = (const bf16x8*)Wb[buf] + lane;
        #pragma unroll
        for (int f = 0; f < 8; ++f) wf[f] = wbl[f * 64];

        // ---- S-phase: each A-frag feeds BOTH tiles (2 independent chains) ----
        f32x16 s0 = zero16(), s1 = zero16();
        const bf16x8* cbl = (const bf16x8*)Cb[buf] + lane;
        #pragma unroll
        for (int ks = 0; ks < 16; ++ks) {
            const bf16x8 A = cbl[ks * 64];
            s0 = __builtin_amdgcn_mfma_f32_32x32x16_bf16(A, xb[0][ks], s0, 0, 0, 0);
            s1 = __builtin_amdgcn_mfma_f32_32x32x16_bf16(A, xb[1][ks], s1, 0, 0, 0);
        }

        // ---- per tile: phi -> pack/exchange -> PV (verified round-3 inner code) ----
        #pragma unroll
        for (int t = 0; t < 2; ++t) {
            const f32x16 S = t ? s1 : s0;
            const float xst = xs[t];
            float p[16];
            #pragma unroll
            for (int g = 0; g < 4; ++g) {
                const float4 a4 = *(const float4*)(ns   + c * 32 + g * 8 + hi * 4);
                const float4 b4 = *(const float4*)(nscs + c * 32 + g * 8 + hi * 4);
                const float4 c4 = *(const float4*)(ts   + c * 32 + g * 8 + hi * 4);
                const float* ap = (const float*)&a4;
                const float* bp = (const float*)&b4;
                const float* cp = (const float*)&c4;
                #pragma unroll
                for (int j = 0; j < 4; ++j) {
                    const float tt = fmaf(cp[j], S[g * 4 + j], fmaf(ap[j], xst, bp[j]));
                    p[g * 4 + j] = EXP2(tt);
                }
            }
            #pragma unroll
            for (int k2 = 0; k2 < 2; ++k2) {
                const int rb = k2 * 8;
                const u32 A = pack_bf16_trunc(p[rb + 0], p[rb + 1]);
                const u32 B = pack_bf16_trunc(p[rb + 2], p[rb + 3]);
                const u32 C = pack_bf16_trunc(p[rb + 4], p[rb + 5]);
                const u32 D = pack_bf16_trunc(p[rb + 6], p[rb + 7]);
                const u32 g0 = hi ? A : C;
                const u32 g1 = hi ? B : D;
                const u32 r0 = (u32)__shfl_xor((int)g0, 32, 64);
                const u32 r1 = (u32)__shfl_xor((int)g1, 32, 64);
                union { u32 u[4]; bf16x8 v; } pa;
                pa.u[0] = hi ? r0 : A;
                pa.u[1] = hi ? r1 : B;
                pa.u[2] = hi ? C : r0;
                pa.u[3] = hi ? D : r1;
                #pragma unroll
                for (int ct = 0; ct < 4; ++ct)
                    acc[t][ct] = __builtin_amdgcn_mfma_f32_32x32x16_bf16(pa.v, wf[ct * 2 + k2], acc[t][ct], 0, 0, 0);
            }
        }

        __syncthreads();   // drains own DMA (vmcnt) + all waves done reading buf
        buf ^= 1;
    }

    // ---- epilogue: out[q][o] = acc + b ----
    float bq[4];
    #pragma unroll
    for (int ct = 0; ct < 4; ++ct) bq[ct] = bvec[ct * 32 + l31];
    #pragma unroll
    for (int t = 0; t < 2; ++t) {
        #pragma unroll
        for (int r = 0; r < 16; ++r) {
            const int q = qb + t * 32 + (r & 3) + 8 * (r >> 2) + 4 * hi;
            #pragma unroll
            for (int ct = 0; ct < 4; ++ct)
                out[(size_t)q * 128 + ct * 32 + l31] = acc[t][ct][r] + bq[ct];
        }
    }
}

extern "C" void kernel_launch(void* const* d_in, const int* in_sizes, int n_in,
                              void* d_out, int out_size, void* d_ws, size_t ws_size,
                              hipStream_t stream) {
    (void)in_sizes; (void)n_in; (void)out_size; (void)ws_size;
    const float* x       = (const float*)d_in[0];
    const float* centers = (const float*)d_in[1];
    const float* sigmas  = (const float*)d_in[2];
    const float* W       = (const float*)d_in[3];
    const float* b       = (const float*)d_in[4];
    float* out = (float*)d_out;

    short* cfrag = (short*)d_ws;                 // 32768 frags * 16B = 512 KB
    short* wfrag = cfrag + 32768 * 8;            // 16384 frags * 16B = 256 KB
    float* ns    = (float*)(wfrag + 16384 * 8);  // 4 KB
    float* nscs  = ns + 1024;                    // 4 KB
    float* ts    = nscs + 1024;                  // 4 KB

    rbf_prep<<<448, 256, 0, stream>>>(centers, sigmas, W, cfrag, wfrag, ns, nscs, ts);
    rbf_main<<<256, 256, 0, stream>>>(x, b, cfrag, wfrag, ns, nscs, ts, out);
}

// Round 6
// 91.742 us; speedup vs baseline: 1.1017x; 1.1017x over previous
//
#include <hip/hip_runtime.h>

typedef __attribute__((ext_vector_type(8))) short bf16x8;
typedef __attribute__((ext_vector_type(16))) float f32x16;
typedef unsigned int u32;
typedef unsigned long long u64;

#define LOG2E 1.44269504088896f

__device__ __forceinline__ short f2bf(float f) {
    union { float f; unsigned u; } v; v.f = f;
    unsigned r = v.u + 0x7fffu + ((v.u >> 16) & 1u);
    return (short)(r >> 16);
}

// float -> OCP e4m3fn byte (RNE, saturate to 448, subnormals to 2^-9 steps)
__device__ __forceinline__ u32 f2e4m3(float f) {
    u32 u = __float_as_uint(f);
    u32 sgn = (u >> 24) & 0x80u;
    u32 mag = u & 0x7fffffffu;
    if (mag >= 0x43E00000u) return sgn | 0x7Eu;       // |f| >= 448 -> max
    if (mag < 0x3C800000u) {                          // |f| < 2^-6 -> subnormal
        u32 q = (u32)(__uint_as_float(mag) * 512.0f + 0.5f);  // [0,8]; 8 == 2^-6 normal
        return sgn | q;
    }
    u32 r = mag + 0x0007FFFFu + ((mag >> 20) & 1u);   // RNE into 3-bit mantissa
    u32 e8 = ((r >> 23) - 120u) & 0xFu;
    u32 m3 = (r >> 20) & 7u;
    return sgn | (e8 << 3) | m3;
}

__device__ __forceinline__ long pack8_e4m3(float4 a, float4 b) {
    u32 lo = f2e4m3(a.x) | (f2e4m3(a.y) << 8) | (f2e4m3(a.z) << 16) | (f2e4m3(a.w) << 24);
    u32 hi = f2e4m3(b.x) | (f2e4m3(b.y) << 8) | (f2e4m3(b.z) << 16) | (f2e4m3(b.w) << 24);
    return (long)(((u64)hi << 32) | lo);
}

#if __has_builtin(__builtin_amdgcn_exp2f)
#define EXP2(x) __builtin_amdgcn_exp2f(x)
#else
#define EXP2(x) __builtin_exp2f(x)
#endif

__device__ __forceinline__ u32 pack_bf16_trunc(float lo, float hi) {
#if __has_builtin(__builtin_amdgcn_perm)
    return __builtin_amdgcn_perm(__float_as_uint(hi), __float_as_uint(lo), 0x07060302u);
#else
    return (__float_as_uint(hi) & 0xFFFF0000u) | (__float_as_uint(lo) >> 16);
#endif
}

__device__ __forceinline__ f32x16 zero16() {
    f32x16 v;
    #pragma unroll
    for (int i = 0; i < 16; ++i) v[i] = 0.f;
    return v;
}

__device__ __forceinline__ void gload16(const void* g, void* l) {
    __builtin_amdgcn_global_load_lds(
        (const __attribute__((address_space(1))) void*)g,
        (__attribute__((address_space(3))) void*)l, 16, 0, 0);
}

// ---------------- prep ----------------
// blocks 0..255  : per-center scalars (log2e-scaled): ns=-s*L, nscs=-s*||c||^2*L, ts=2s*L
// blocks 256..383: centers -> cfrag8 (fp8 e4m3), 32x32x16 fp8 A-frag order:
//                  slot s=[g][ks][lane], 8B: m=g*32+(l&31), k=ks*16+(l>>5)*8 (+j, byte j)
// blocks 384..447: W -> wfrag (bf16), 32x32x16 B-frag order: slot s=[g][ct][k2][lane]
__global__ __launch_bounds__(256) void rbf_prep(
    const float* __restrict__ centers, const float* __restrict__ sigmas,
    const float* __restrict__ W,
    char* __restrict__ cfrag8, short* __restrict__ wfrag,
    float* __restrict__ ns, float* __restrict__ nscs, float* __restrict__ ts)
{
    const int tid = threadIdx.x;
    const int bid = blockIdx.x;
    if (bid < 256) {
        const int lane = tid & 63, w = tid >> 6;
        const int row = bid * 4 + w;
        const float4 v = ((const float4*)(centers + (size_t)row * 256))[lane];
        float s = v.x*v.x + v.y*v.y + v.z*v.z + v.w*v.w;
        #pragma unroll
        for (int off = 32; off >= 1; off >>= 1) s += __shfl_xor(s, off, 64);
        if (lane == 0) {
            const float sg = sigmas[row];
            ns[row]   = -sg * LOG2E;
            nscs[row] = -sg * s * LOG2E;
            ts[row]   = 2.0f * sg * LOG2E;
        }
    } else if (bid < 384) {
        const int s = (bid - 256) * 256 + tid;               // 0..32767
        const int g = s >> 10, ks = (s >> 6) & 15, lane = s & 63;
        const int m = g * 32 + (lane & 31);
        const int k = ks * 16 + (lane >> 5) * 8;
        const float4 a = *(const float4*)(centers + (size_t)m * 256 + k);
        const float4 b = *(const float4*)(centers + (size_t)m * 256 + k + 4);
        *(long*)(cfrag8 + (size_t)s * 8) = pack8_e4m3(a, b);
    } else {
        const int s = (bid - 384) * 256 + tid;               // 0..16383
        const int g = s >> 9, ct = (s >> 7) & 3, k2 = (s >> 6) & 1, lane = s & 63;
        const int o = ct * 32 + (lane & 31);
        const int m = g * 32 + k2 * 16 + (lane >> 5) * 8;
        const float4 a = *(const float4*)(W + (size_t)o * 1024 + m);
        const float4 b = *(const float4*)(W + (size_t)o * 1024 + m + 4);
        bf16x8 t;
        t[0]=f2bf(a.x); t[1]=f2bf(a.y); t[2]=f2bf(a.z); t[3]=f2bf(a.w);
        t[4]=f2bf(b.x); t[5]=f2bf(b.y); t[6]=f2bf(b.z); t[7]=f2bf(b.w);
        ((bf16x8*)wfrag)[s] = t;
    }
}

// ---------------- main ----------------
// Thin waves (32 q-rows), 4 waves/block, grid 512, 2 blocks/CU (LDS 64KB).
// 16 chunks of 64 centers. Per chunk t (parity P = t&1):
//   [PV(t-1): reg-only MFMAs, W-frags from Wb[P^1]]  <- fills MFMA pipe at chunk top
//   mid-barrier (cheap: nothing outstanding)         <- protects Wb[P^1] from DMA below
//   [DMA chunk t+1 -> Cb8/Wb[P^1]]
//   [S-phase: fp8 MFMA, A from Cb8[P], X fp8 in regs]
//   [exp/pack -> pa regs for next chunk's PV]
//   end-barrier (drains DMA; DMA had S+exp to land)
__global__ __launch_bounds__(256, 2) void rbf_main(
    const float* __restrict__ x, const float* __restrict__ bvec,
    const char* __restrict__ cfrag8, const short* __restrict__ wfrag,
    const float* __restrict__ ns, const float* __restrict__ nscs,
    const float* __restrict__ ts, float* __restrict__ out)
{
    __shared__ char  Cb8[2][16384];   // 16 KB/buf: 32 fp8 A-frags x 512B
    __shared__ short Wb[2][8192];     // 16 KB/buf: 16 bf16 B-frags x 1KB

    const int tid = threadIdx.x;
    const int lane = tid & 63;
    const int l31 = lane & 31;
    const int hi = lane >> 5;
    const int w = tid >> 6;
    const int qb = blockIdx.x * 128 + w * 32;

    // ---- stage chunk 0 into parity-0 buffers (async under X prologue) ----
    #pragma unroll
    for (int i = 0; i < 4; ++i) {
        const int ig = w * 4 + i;
        gload16(cfrag8 + ig * 1024 + lane * 16, &Cb8[0][ig * 1024]);
        gload16(wfrag + ig * 512 + lane * 8, &Wb[0][ig * 512]);
    }

    // ---- X -> fp8 B-frags in regs (lane: q=qb+l31, k=ks*16+hi*8+j) + xs fp32 ----
    long xq8[16];
    const float* xr = x + (size_t)(qb + l31) * 256 + hi * 8;
    float ss = 0.f;
    #pragma unroll
    for (int ks = 0; ks < 16; ++ks) {
        const float4 a = *(const float4*)(xr + ks * 16);
        const float4 b = *(const float4*)(xr + ks * 16 + 4);
        ss += a.x*a.x + a.y*a.y + a.z*a.z + a.w*a.w
            + b.x*b.x + b.y*b.y + b.z*b.z + b.w*b.w;
        xq8[ks] = pack8_e4m3(a, b);
    }
    ss += __shfl_xor(ss, 32, 64);
    const float xs = ss;

    f32x16 acc[4];
    #pragma unroll
    for (int ct = 0; ct < 4; ++ct) acc[ct] = zero16();
    bf16x8 pav[2][2];   // PV A-frags carried to next chunk (static-indexed only)

    __syncthreads();    // drains chunk-0 DMA + X loads

    for (int t = 0; t < 16; ++t) {
        const int P = t & 1;

        // ---- deferred PV(t-1): register-only MFMAs, W from old buffer ----
        if (t > 0) {
            const bf16x8* wold = (const bf16x8*)&Wb[P ^ 1][0];
            __builtin_amdgcn_s_setprio(1);
            #pragma unroll
            for (int grp = 0; grp < 2; ++grp) {
                bf16x8 wv[8];
                #pragma unroll
                for (int f = 0; f < 8; ++f) wv[f] = wold[(grp * 8 + f) * 64 + lane];
                #pragma unroll
                for (int ct = 0; ct < 4; ++ct)
                    #pragma unroll
                    for (int k2 = 0; k2 < 2; ++k2)
                        acc[ct] = __builtin_amdgcn_mfma_f32_32x32x16_bf16(
                            pav[grp][k2], wv[ct * 2 + k2], acc[ct], 0, 0, 0);
            }
            __builtin_amdgcn_s_setprio(0);
        }

        __syncthreads();   // cheap: protects Wb[P^1] before DMA overwrites it

        // ---- DMA chunk t+1 into parity P^1 buffers ----
        if (t < 15) {
            const char* csrc = cfrag8 + (size_t)(t + 1) * 16384;
            const short* wsrc = wfrag + (size_t)(t + 1) * 8192;
            #pragma unroll
            for (int i = 0; i < 4; ++i) {
                const int ig = w * 4 + i;
                gload16(csrc + ig * 1024 + lane * 16, &Cb8[P ^ 1][ig * 1024]);
                gload16(wsrc + ig * 512 + lane * 8, &Wb[P ^ 1][ig * 512]);
            }
        }

        // ---- S-phase: two independent fp8 MFMA chains (groups of 32 centers) ----
        const char* cbase = &Cb8[P][0];
        f32x16 s0 = zero16(), s1 = zero16();
        __builtin_amdgcn_s_setprio(1);
        #pragma unroll
        for (int ks = 0; ks < 16; ++ks) {
            const long A0 = *(const long*)(cbase + ks * 512 + lane * 8);
            const long A1 = *(const long*)(cbase + 8192 + ks * 512 + lane * 8);
            s0 = __builtin_amdgcn_mfma_f32_32x32x16_fp8_fp8(A0, xq8[ks], s0, 0, 0, 0);
            s1 = __builtin_amdgcn_mfma_f32_32x32x16_fp8_fp8(A1, xq8[ks], s1, 0, 0, 0);
        }
        __builtin_amdgcn_s_setprio(0);

        // ---- phi = exp2(ts*S + ns*xs + nscs) ; pack -> pa for next chunk's PV ----
        #pragma unroll
        for (int grp = 0; grp < 2; ++grp) {
            const f32x16 S = grp ? s1 : s0;
            const int cb = t * 64 + grp * 32;
            float p[16];
            #pragma unroll
            for (int g4 = 0; g4 < 4; ++g4) {
                const float4 a4 = *(const float4*)(ns   + cb + g4 * 8 + hi * 4);
                const float4 b4 = *(const float4*)(nscs + cb + g4 * 8 + hi * 4);
                const float4 c4 = *(const float4*)(ts   + cb + g4 * 8 + hi * 4);
                const float* ap = (const float*)&a4;
                const float* bp = (const float*)&b4;
                const float* cp = (const float*)&c4;
                #pragma unroll
                for (int j = 0; j < 4; ++j) {
                    const float tt = fmaf(cp[j], S[g4 * 4 + j], fmaf(ap[j], xs, bp[j]));
                    p[g4 * 4 + j] = EXP2(tt);
                }
            }
            #pragma unroll
            for (int k2 = 0; k2 < 2; ++k2) {
                const int rb = k2 * 8;
                const u32 A = pack_bf16_trunc(p[rb + 0], p[rb + 1]);
                const u32 B = pack_bf16_trunc(p[rb + 2], p[rb + 3]);
                const u32 C = pack_bf16_trunc(p[rb + 4], p[rb + 5]);
                const u32 D = pack_bf16_trunc(p[rb + 6], p[rb + 7]);
                const u32 g0 = hi ? A : C;
                const u32 g1 = hi ? B : D;
                const u32 r0 = (u32)__shfl_xor((int)g0, 32, 64);
                const u32 r1 = (u32)__shfl_xor((int)g1, 32, 64);
                union { u32 u[4]; bf16x8 v; } pa;
                pa.u[0] = hi ? r0 : A;
                pa.u[1] = hi ? r1 : B;
                pa.u[2] = hi ? C : r0;
                pa.u[3] = hi ? D : r1;
                pav[grp][k2] = pa.v;
            }
        }

        __syncthreads();   // drains this chunk's DMA; all waves done with Cb8[P]
    }

    // ---- final PV(15): W is in parity-1 buffer, untouched since chunk 14 staged it ----
    {
        const bf16x8* wold = (const bf16x8*)&Wb[1][0];
        #pragma unroll
        for (int grp = 0; grp < 2; ++grp) {
            bf16x8 wv[8];
            #pragma unroll
            for (int f = 0; f < 8; ++f) wv[f] = wold[(grp * 8 + f) * 64 + lane];
            #pragma unroll
            for (int ct = 0; ct < 4; ++ct)
                #pragma unroll
                for (int k2 = 0; k2 < 2; ++k2)
                    acc[ct] = __builtin_amdgcn_mfma_f32_32x32x16_bf16(
                        pav[grp][k2], wv[ct * 2 + k2], acc[ct], 0, 0, 0);
        }
    }

    // ---- epilogue: out[q][o] = acc + b ; D: col=l31 (o), row=(r&3)+8*(r>>2)+4*hi (q) ----
    float bq[4];
    #pragma unroll
    for (int ct = 0; ct < 4; ++ct) bq[ct] = bvec[ct * 32 + l31];
    #pragma unroll
    for (int r = 0; r < 16; ++r) {
        const int q = qb + (r & 3) + 8 * (r >> 2) + 4 * hi;
        #pragma unroll
        for (int ct = 0; ct < 4; ++ct)
            out[(size_t)q * 128 + ct * 32 + l31] = acc[ct][r] + bq[ct];
    }
}

extern "C" void kernel_launch(void* const* d_in, const int* in_sizes, int n_in,
                              void* d_out, int out_size, void* d_ws, size_t ws_size,
                              hipStream_t stream) {
    (void)in_sizes; (void)n_in; (void)out_size; (void)ws_size;
    const float* x       = (const float*)d_in[0];
    const float* centers = (const float*)d_in[1];
    const float* sigmas  = (const float*)d_in[2];
    const float* W       = (const float*)d_in[3];
    const float* b       = (const float*)d_in[4];
    float* out = (float*)d_out;

    char*  cfrag8 = (char*)d_ws;                     // 32768 slots * 8B  = 256 KB
    short* wfrag  = (short*)(cfrag8 + 32768 * 8);    // 16384 slots * 16B = 256 KB
    float* ns     = (float*)(wfrag + 16384 * 8);     // 4 KB
    float* nscs   = ns + 1024;                       // 4 KB
    float* ts     = nscs + 1024;                     // 4 KB

    rbf_prep<<<448, 256, 0, stream>>>(centers, sigmas, W, cfrag8, wfrag, ns, nscs, ts);
    rbf_main<<<512, 256, 0, stream>>>(x, b, cfrag8, wfrag, ns, nscs, ts, out);
}